// Round 9
// baseline (201.945 us; speedup 1.0000x reference)
//
#include <hip/hip_runtime.h>

// B=4, C=12, D=32, H=128, W=128. S = D*H*W = 524288 voxels per b.
// R9: stage-ahead double-buffered LDS pipeline. R1/R2/R7/R8 all ~56-61us
// (~1.9 TB/s): R8 proved register-destination serialization isn't the whole
// story; its stage->drain->compute sequence left the memory pipe idle during
// compute. R9: while computing tile t from buffer cur, tile t+1's
// global_load_lds are in flight into the other buffer; the barrier's
// vmcnt(0) drain retires nearly-done loads. 512 blocks (2/CU), 128 thr,
// 8 tiles/block, 52KB LDS (dbuf 2x24KB + targets), contiguous 16KB/channel
// slabs per block.

#define S4 131072           // S/4 float4 groups per (b,c) plane
#define BLOCKS_PER_B 128    // grid 512 = 2 blocks/CU
#define THREADS 128
#define GROUPS 128          // float4-groups per tile
#define NTILES 8
#define NVOX 524288.0f
#define SMOOTH 1e-5f
#define L2E 1.4426950408889634f
#define LN2 0.6931471805599453f

#define WRED(v) { v += __shfl_down(v,32); v += __shfl_down(v,16); \
                  v += __shfl_down(v,8);  v += __shfl_down(v,4);  \
                  v += __shfl_down(v,2);  v += __shfl_down(v,1); }

__global__ void zero_acc(float* __restrict__ acc) {
  acc[blockIdx.x * 256 + threadIdx.x] = 0.f;   // 2048 floats
}

// 16B global->LDS direct copy: HW writes ldsbase + lane*16 (wave-uniform base).
__device__ __forceinline__ void gload_lds16(const float4* g, float4* ldsbase) {
  __builtin_amdgcn_global_load_lds(
      (const __attribute__((address_space(1))) void*)g,
      (__attribute__((address_space(3))) void*)ldsbase, 16, 0, 0);
}

// Per-voxel scalar tail; CM in {x,y,z,w}. CE sums in log2 units.
#define TAIL(CM) {                                                             \
  const int tv = tg.CM;                                                        \
  const bool t0 = (tv == 0), t1 = (tv == id1), t2 = (tv == id2);               \
  c1f += t1 ? 1.f : 0.f;  c2f += t2 ? 1.f : 0.f;                               \
  p0S += t0 ? g0.CM : 0.f; p1S += t1 ? g1.CM : 0.f; p2S += t2 ? g2.CM : 0.f;   \
  const float pt = t1 ? g1.CM : (t2 ? g2.CM : 0.f);                            \
  cesE2 += __builtin_amdgcn_logf(prod.CM * __builtin_amdgcn_rcpf(1.f + pt));   \
  const float s3 = __builtin_amdgcn_exp2f(g0.CM * L2E)                         \
                 + __builtin_amdgcn_exp2f(g1.CM * L2E)                         \
                 + __builtin_amdgcn_exp2f(g2.CM * L2E);                        \
  const float gt = t0 ? g0.CM : (t1 ? g1.CM : g2.CM);                          \
  ces2 += __builtin_amdgcn_logf(s3) - gt * L2E;                                \
}

// Stage tile T of this block into buffer PB (13 dependency-free VMEM ops).
#define STAGE(T, PB) {                                                         \
  const int g = base + (T) * GROUPS + tid;                                     \
  _Pragma("unroll")                                                            \
  for (int c = 0; c < 12; ++c)                                                 \
    gload_lds16(&inB[(size_t)c * S4 + g], &sbuf[PB][c][wv << 6]);              \
  gload_lds16((const float4*)&tgB[g], (float4*)&stg[PB][wv << 6]);             \
}

// Compute tile resident in buffer PB.
#define COMPUTE(PB) {                                                          \
  float4 xv[12];                                                               \
  _Pragma("unroll")                                                            \
  for (int c = 0; c < 12; ++c) {                                               \
    const float4 v = sbuf[PB][c][tid];                                         \
    xv[c].x = __builtin_amdgcn_exp2f(v.x * L2E);                               \
    xv[c].y = __builtin_amdgcn_exp2f(v.y * L2E);                               \
    xv[c].z = __builtin_amdgcn_exp2f(v.z * L2E);                               \
    xv[c].w = __builtin_amdgcn_exp2f(v.w * L2E);                               \
  }                                                                            \
  float4 es = xv[0];                                                           \
  _Pragma("unroll")                                                            \
  for (int c = 1; c < 12; ++c) {                                               \
    es.x += xv[c].x; es.y += xv[c].y; es.z += xv[c].z; es.w += xv[c].w;        \
  }                                                                            \
  float4 r;                                                                    \
  r.x = __builtin_amdgcn_rcpf(es.x); r.y = __builtin_amdgcn_rcpf(es.y);        \
  r.z = __builtin_amdgcn_rcpf(es.z); r.w = __builtin_amdgcn_rcpf(es.w);        \
  float4 prod = make_float4(1.f, 1.f, 1.f, 1.f);                               \
  _Pragma("unroll")                                                            \
  for (int c = 0; c < 12; ++c) {                                               \
    float4 p;                                                                  \
    p.x = xv[c].x * r.x; p.y = xv[c].y * r.y;                                  \
    p.z = xv[c].z * r.z; p.w = xv[c].w * r.w;                                  \
    aZ[c] += (p.x*p.x + p.y*p.y) + (p.z*p.z + p.w*p.w);                        \
    aP[c] += (p.x + p.y) + (p.z + p.w);                                        \
    if (c > 0) {                                                               \
      prod.x = fmaf(prod.x, p.x, prod.x);                                      \
      prod.y = fmaf(prod.y, p.y, prod.y);                                      \
      prod.z = fmaf(prod.z, p.z, prod.z);                                      \
      prod.w = fmaf(prod.w, p.w, prod.w);                                      \
    }                                                                          \
  }                                                                            \
  const float4 v1  = sbuf[PB][id1][tid];                                       \
  const float4 vv2 = sbuf[PB][id2c][tid];                                      \
  float4 g0, g1, g2;                                                           \
  g0.x = xv[0].x * r.x; g0.y = xv[0].y * r.y;                                  \
  g0.z = xv[0].z * r.z; g0.w = xv[0].w * r.w;                                  \
  g1.x = __builtin_amdgcn_exp2f(v1.x * L2E) * r.x;                             \
  g1.y = __builtin_amdgcn_exp2f(v1.y * L2E) * r.y;                             \
  g1.z = __builtin_amdgcn_exp2f(v1.z * L2E) * r.z;                             \
  g1.w = __builtin_amdgcn_exp2f(v1.w * L2E) * r.w;                             \
  g2.x = v2 ? __builtin_amdgcn_exp2f(vv2.x * L2E) * r.x : -1e30f;              \
  g2.y = v2 ? __builtin_amdgcn_exp2f(vv2.y * L2E) * r.y : -1e30f;              \
  g2.z = v2 ? __builtin_amdgcn_exp2f(vv2.z * L2E) * r.z : -1e30f;              \
  g2.w = v2 ? __builtin_amdgcn_exp2f(vv2.w * L2E) * r.w : -1e30f;              \
  const int4 tg = stg[PB][tid];                                                \
  TAIL(x); TAIL(y); TAIL(z); TAIL(w);                                          \
}

// acc slot layout (64B-spread): acc[(b*32+v)<<4]
//  v: 0..11 aZ[c]=sum p_c^2   12..23 aP[c]=sum p_c
//  24 ces2  25 cesE2  26 c1  27 c2  28 p0S  29 p1S  30 p2S  31 pad
__global__ __launch_bounds__(THREADS, 1)
void marg_main(const float4* __restrict__ inp, const int4* __restrict__ tgtp,
               const int* __restrict__ task_id, float* __restrict__ acc) {
  __shared__ float4 sbuf[2][12][GROUPS];   // 2 x 24 KB
  __shared__ int4   stg[2][GROUPS];        // 2 x 2 KB
  __shared__ float  red[2][32];

  const int b    = blockIdx.x / BLOCKS_PER_B;
  const int blk  = blockIdx.x % BLOCKS_PER_B;
  const int tid  = threadIdx.x;
  const int wv   = tid >> 6;
  const int lane = tid & 63;
  const int t    = task_id[b];
  const int id1  = (t <= 4) ? 2*t + 1 : t + 5;
  const int id2  = (t <= 3) ? 2*t + 2 : -1;
  const bool v2  = (id2 >= 0);
  const int id2c = v2 ? id2 : 0;

  const float4* inB = inp  + (size_t)b * 12 * S4;
  const int4*   tgB = tgtp + (size_t)b * S4;
  const int base = blk * (NTILES * GROUPS);   // contiguous 16KB/channel slab

  float aZ[12], aP[12];
  #pragma unroll
  for (int c = 0; c < 12; ++c) { aZ[c] = 0.f; aP[c] = 0.f; }
  float ces2=0.f, cesE2=0.f, c1f=0.f, c2f=0.f, p0S=0.f, p1S=0.f, p2S=0.f;

  // prologue: stage tile 0
  STAGE(0, 0);
  __syncthreads();

  // pipeline: stage(t+1) in flight during compute(t); barrier drains both
  #pragma unroll
  for (int tt = 0; tt < NTILES; ++tt) {
    const int cur = tt & 1, nxt = cur ^ 1;
    if (tt + 1 < NTILES) STAGE(tt + 1, nxt);
    COMPUTE(cur);
    __syncthreads();
  }

  // ---- block reduction (2 waves): shuffle tree + tiny LDS ----
  WRED(ces2); WRED(cesE2); WRED(c1f); WRED(c2f);
  WRED(p0S);  WRED(p1S);   WRED(p2S);
  #pragma unroll
  for (int c = 0; c < 12; ++c) { WRED(aZ[c]); WRED(aP[c]); }

  if (lane == 0) {
    float* rw = red[wv];
    #pragma unroll
    for (int c = 0; c < 12; ++c) { rw[c] = aZ[c]; rw[12 + c] = aP[c]; }
    rw[24] = ces2; rw[25] = cesE2; rw[26] = c1f; rw[27] = c2f;
    rw[28] = p0S;  rw[29] = p1S;   rw[30] = p2S; rw[31] = 0.f;
  }
  __syncthreads();
  if (tid < 32) {
    const float sv = red[0][tid] + red[1][tid];
    atomicAdd(acc + ((b * 32 + tid) << 4), sv);
  }
}

__global__ void finalize(const float* __restrict__ acc,
                         const int* __restrict__ task_id,
                         float* __restrict__ out) {
  if (threadIdx.x != 0) return;
  float lmd = 0.f, lmce = 0.f, led = 0.f, lece = 0.f;
  for (int b = 0; b < 4; ++b) {
    const int t   = task_id[b];
    const int id1 = (t <= 4) ? 2*t + 1 : t + 5;
    const int id2 = (t <= 3) ? 2*t + 2 : -1;
    #define A(v) acc[((b * 32 + (v))) << 4]

    lmce += A(24) * LN2 / NVOX;
    lece += A(25) * LN2 / NVOX;

    const float c1 = A(26), c2 = A(27);
    const float y0 = NVOX - c1 - c2;
    const float d0 = (2.f*A(28) + SMOOTH) / (A(0)   + y0 + SMOOTH);
    const float d1 = (2.f*A(29) + SMOOTH) / (A(id1) + c1 + SMOOTH);
    float d2 = 1.f;
    if (id2 >= 0)
      d2 = (2.f*A(30) + SMOOTH) / (A(id2) + c2 + SMOOTH);
    lmd += (1.f - d0) + (1.f - d1) + (1.f - d2);

    led += SMOOTH / (A(0) + SMOOTH);
    for (int c = 1; c < 12; ++c) {
      const float ptc  = (c == id1) ? A(29) : ((c == id2) ? A(30) : 0.f);
      const float cntc = (c == id1) ? c1    : ((c == id2) ? c2    : 0.f);
      const float inter = A(12 + c) - ptc;
      const float ye    = NVOX - cntc;
      led += (2.f*inter + SMOOTH) / (A(c) + ye + SMOOTH);
    }
    #undef A
  }
  out[0] = lmd  * 0.25f;
  out[1] = lmce * 0.25f;
  out[2] = led  * 0.25f;
  out[3] = lece * 0.25f;
}

extern "C" void kernel_launch(void* const* d_in, const int* in_sizes, int n_in,
                              void* d_out, int out_size, void* d_ws, size_t ws_size,
                              hipStream_t stream) {
  const float* inputs  = (const float*)d_in[0];
  const int*   targets = (const int*)d_in[1];
  const int*   task_id = (const int*)d_in[2];
  float* out = (float*)d_out;
  float* acc = (float*)d_ws;

  zero_acc<<<dim3(8), 256, 0, stream>>>(acc);
  marg_main<<<dim3(4 * BLOCKS_PER_B), THREADS, 0, stream>>>(
      (const float4*)inputs, (const int4*)targets, task_id, acc);
  finalize<<<1, 64, 0, stream>>>(acc, task_id, out);
}

// Round 10
// 194.643 us; speedup vs baseline: 1.0375x; 1.0375x over previous
//
#include <hip/hip_runtime.h>

// B=4, C=12, D=32, H=128, W=128. S = D*H*W = 524288 voxels per b.
// R10: max-TLP bet. All prior rounds ran <=16 waves/CU and plateaued at
// marg ~56-75us (~1.9 TB/s effective). R4 proved the lean math fits VGPR=60.
// This round: 1 float4-group per thread, 2048 blocks x 256 thr, 
// __launch_bounds__(256,8) -> VGPR cap 64 -> 32 waves/CU. Per-wave loads get
// serialized at this register budget (R4's disease) but 32 waves x ~4KB in
// flight = ~128KB/CU outstanding: TLP substitutes for the per-wave MLP the
// compiler refuses to emit. No switches, no extra loads (g1/g2 via in-loop
// wave-uniform cndmask), R2's proven shuffle-tree + spread-atomic epilogue.

#define S4 131072           // S/4 float4 groups per (b,c) plane
#define BLOCKS_PER_B 512    // 512*256 threads = S4 groups, 1 group/thread
#define THREADS 256
#define NVOX 524288.0f
#define SMOOTH 1e-5f
#define L2E 1.4426950408889634f
#define LN2 0.6931471805599453f

#define WRED(v) { v += __shfl_down(v,32); v += __shfl_down(v,16); \
                  v += __shfl_down(v,8);  v += __shfl_down(v,4);  \
                  v += __shfl_down(v,2);  v += __shfl_down(v,1); }

__global__ void zero_acc(float* __restrict__ acc) {
  acc[blockIdx.x * 256 + threadIdx.x] = 0.f;   // 2048 floats
}

// Per-voxel scalar tail; CM in {x,y,z,w}. CE sums in log2 units.
#define TAIL(CM) {                                                             \
  const int tv = tg.CM;                                                        \
  const bool t0 = (tv == 0), t1 = (tv == id1), t2 = (tv == id2);               \
  c1f += t1 ? 1.f : 0.f;  c2f += t2 ? 1.f : 0.f;                               \
  p0S += t0 ? g0.CM : 0.f; p1S += t1 ? g1.CM : 0.f; p2S += t2 ? g2.CM : 0.f;   \
  const float pt = t1 ? g1.CM : (t2 ? g2.CM : 0.f);                            \
  cesE2 += __builtin_amdgcn_logf(prod.CM * __builtin_amdgcn_rcpf(1.f + pt));   \
  const float s3 = __builtin_amdgcn_exp2f(g0.CM * L2E)                         \
                 + __builtin_amdgcn_exp2f(g1.CM * L2E)                         \
                 + __builtin_amdgcn_exp2f(g2.CM * L2E);                        \
  const float gt = t0 ? g0.CM : (t1 ? g1.CM : g2.CM);                          \
  ces2 += __builtin_amdgcn_logf(s3) - gt * L2E;                                \
}

// acc slot layout (64B-spread): acc[(b*32+v)<<4]
//  v: 0..11 aZ[c]=sum p_c^2   12..23 aP[c]=sum p_c
//  24 ces2  25 cesE2  26 c1  27 c2  28 p0S  29 p1S  30 p2S  31 pad
__global__ __launch_bounds__(THREADS, 8)   // VGPR cap 64 -> 32 waves/CU
void marg_main(const float4* __restrict__ inp, const int4* __restrict__ tgtp,
               const int* __restrict__ task_id, float* __restrict__ acc) {
  const int b   = blockIdx.x >> 9;          // / BLOCKS_PER_B
  const int blk = blockIdx.x & 511;
  const int tid = threadIdx.x;
  const int t   = task_id[b];
  const int id1 = (t <= 4) ? 2*t + 1 : t + 5;
  const int id2 = (t <= 3) ? 2*t + 2 : -1;
  const bool v2 = (id2 >= 0);

  const float4* inB = inp  + (size_t)b * 12 * S4;
  const int4*   tgB = tgtp + (size_t)b * S4;
  const int g = blk * THREADS + tid;

  // one float4-group (4 voxels) per thread
  float4 e[12];
  #pragma unroll
  for (int c = 0; c < 12; ++c) e[c] = inB[(size_t)c * S4 + g];
  const int4 tg = tgB[g];

  // softmax without max-subtraction (inputs ~N(0,1): |x|<6, fp32-safe)
  #pragma unroll
  for (int c = 0; c < 12; ++c) {
    e[c].x = __builtin_amdgcn_exp2f(e[c].x * L2E);
    e[c].y = __builtin_amdgcn_exp2f(e[c].y * L2E);
    e[c].z = __builtin_amdgcn_exp2f(e[c].z * L2E);
    e[c].w = __builtin_amdgcn_exp2f(e[c].w * L2E);
  }
  float4 es = e[0];
  #pragma unroll
  for (int c = 1; c < 12; ++c) {
    es.x += e[c].x; es.y += e[c].y; es.z += e[c].z; es.w += e[c].w;
  }
  float4 r;
  r.x = __builtin_amdgcn_rcpf(es.x); r.y = __builtin_amdgcn_rcpf(es.y);
  r.z = __builtin_amdgcn_rcpf(es.z); r.w = __builtin_amdgcn_rcpf(es.w);

  // fused per-channel loop: aZ/aP scalars, prod(1+p), uniform-mask g1/g2
  float aZ[12], aP[12];
  float4 prod = make_float4(1.f, 1.f, 1.f, 1.f);
  float4 g0, g1, g2;
  g1 = make_float4(0.f, 0.f, 0.f, 0.f);
  g2 = make_float4(0.f, 0.f, 0.f, 0.f);
  #pragma unroll
  for (int c = 0; c < 12; ++c) {
    float4 p;
    p.x = e[c].x * r.x; p.y = e[c].y * r.y;
    p.z = e[c].z * r.z; p.w = e[c].w * r.w;
    aZ[c] = (p.x*p.x + p.y*p.y) + (p.z*p.z + p.w*p.w);
    aP[c] = (p.x + p.y) + (p.z + p.w);
    if (c == 0) {
      g0 = p;
    } else {
      prod.x = fmaf(prod.x, p.x, prod.x);
      prod.y = fmaf(prod.y, p.y, prod.y);
      prod.z = fmaf(prod.z, p.z, prod.z);
      prod.w = fmaf(prod.w, p.w, prod.w);
      const bool m1 = (c == id1);    // wave-uniform mask -> cndmask
      g1.x = m1 ? p.x : g1.x; g1.y = m1 ? p.y : g1.y;
      g1.z = m1 ? p.z : g1.z; g1.w = m1 ? p.w : g1.w;
      const bool m2 = (c == id2);
      g2.x = m2 ? p.x : g2.x; g2.y = m2 ? p.y : g2.y;
      g2.z = m2 ? p.z : g2.z; g2.w = m2 ? p.w : g2.w;
    }
  }
  // invalid structure-2: force g2 to -1e30 so its exp2 term vanishes
  if (!v2) g2 = make_float4(-1e30f, -1e30f, -1e30f, -1e30f);

  float ces2=0.f, cesE2=0.f, c1f=0.f, c2f=0.f, p0S=0.f, p1S=0.f, p2S=0.f;
  TAIL(x); TAIL(y); TAIL(z); TAIL(w);

  // ---- block reduction: shuffle tree + tiny LDS ----
  WRED(ces2); WRED(cesE2); WRED(c1f); WRED(c2f);
  WRED(p0S);  WRED(p1S);   WRED(p2S);
  #pragma unroll
  for (int c = 0; c < 12; ++c) { WRED(aZ[c]); WRED(aP[c]); }

  __shared__ float red[4][32];
  const int lane = tid & 63;
  const int wv   = tid >> 6;
  if (lane == 0) {
    float* rw = red[wv];
    #pragma unroll
    for (int c = 0; c < 12; ++c) { rw[c] = aZ[c]; rw[12 + c] = aP[c]; }
    rw[24] = ces2; rw[25] = cesE2; rw[26] = c1f; rw[27] = c2f;
    rw[28] = p0S;  rw[29] = p1S;   rw[30] = p2S; rw[31] = 0.f;
  }
  __syncthreads();
  if (tid < 32) {
    const float sv = red[0][tid] + red[1][tid] + red[2][tid] + red[3][tid];
    atomicAdd(acc + ((b * 32 + tid) << 4), sv);
  }
}

__global__ void finalize(const float* __restrict__ acc,
                         const int* __restrict__ task_id,
                         float* __restrict__ out) {
  if (threadIdx.x != 0) return;
  float lmd = 0.f, lmce = 0.f, led = 0.f, lece = 0.f;
  for (int b = 0; b < 4; ++b) {
    const int t   = task_id[b];
    const int id1 = (t <= 4) ? 2*t + 1 : t + 5;
    const int id2 = (t <= 3) ? 2*t + 2 : -1;
    #define A(v) acc[((b * 32 + (v))) << 4]

    lmce += A(24) * LN2 / NVOX;
    lece += A(25) * LN2 / NVOX;

    const float c1 = A(26), c2 = A(27);
    const float y0 = NVOX - c1 - c2;
    const float d0 = (2.f*A(28) + SMOOTH) / (A(0)   + y0 + SMOOTH);
    const float d1 = (2.f*A(29) + SMOOTH) / (A(id1) + c1 + SMOOTH);
    float d2 = 1.f;
    if (id2 >= 0)
      d2 = (2.f*A(30) + SMOOTH) / (A(id2) + c2 + SMOOTH);
    lmd += (1.f - d0) + (1.f - d1) + (1.f - d2);

    led += SMOOTH / (A(0) + SMOOTH);
    for (int c = 1; c < 12; ++c) {
      const float ptc  = (c == id1) ? A(29) : ((c == id2) ? A(30) : 0.f);
      const float cntc = (c == id1) ? c1    : ((c == id2) ? c2    : 0.f);
      const float inter = A(12 + c) - ptc;
      const float ye    = NVOX - cntc;
      led += (2.f*inter + SMOOTH) / (A(c) + ye + SMOOTH);
    }
    #undef A
  }
  out[0] = lmd  * 0.25f;
  out[1] = lmce * 0.25f;
  out[2] = led  * 0.25f;
  out[3] = lece * 0.25f;
}

extern "C" void kernel_launch(void* const* d_in, const int* in_sizes, int n_in,
                              void* d_out, int out_size, void* d_ws, size_t ws_size,
                              hipStream_t stream) {
  const float* inputs  = (const float*)d_in[0];
  const int*   targets = (const int*)d_in[1];
  const int*   task_id = (const int*)d_in[2];
  float* out = (float*)d_out;
  float* acc = (float*)d_ws;

  zero_acc<<<dim3(8), 256, 0, stream>>>(acc);
  marg_main<<<dim3(4 * BLOCKS_PER_B), THREADS, 0, stream>>>(
      (const float4*)inputs, (const int4*)targets, task_id, acc);
  finalize<<<1, 64, 0, stream>>>(acc, task_id, out);
}